// Round 3
// baseline (490.445 us; speedup 1.0000x reference)
//
#include <hip/hip_runtime.h>
#include <cstddef>

namespace {
constexpr int kDim = 2048;
constexpr int kS = 4;
constexpr int kSV = 5;   // S + V
constexpr int kB = 4;
constexpr int kN = 2048;
constexpr float kEps = 1e-5f;
constexpr int kThreads = 256;
constexpr int kWaves = kThreads / 64;
}

// One block per (b, n). Each thread owns 8 d-elements: d = 4*tid + {0..3} and
// d = 4*tid + 1024 + {0..3}  (two coalesced float4 chunks, 16 B/lane).
__global__ __launch_bounds__(kThreads) void hyperconn_kernel(
    const float* __restrict__ res,          // (B*S, N, DIM)
    const float* __restrict__ norm_w,       // (DIM,)
    const float* __restrict__ static_beta,  // (S,)
    const float* __restrict__ static_alpha, // (S, SV)
    const float* __restrict__ alpha_fn,     // (DIM, SV)
    const float* __restrict__ alpha_scale_p,// (1,)
    const float* __restrict__ beta_fn,      // (DIM,)
    const float* __restrict__ beta_scale_p, // (1,)
    float* __restrict__ out)                // (B*S, N, DIM)
{
  const int bid = blockIdx.x;
  const int b = bid / kN;
  const int n = bid % kN;
  const int tid = threadIdx.x;
  const int lane = tid & 63;
  const int wave = tid >> 6;

  __shared__ float red[kWaves][24];
  __shared__ float ab[24];  // ab[s*6+t], t<5: alpha[s][t]; t==5: beta[s]

  const size_t plane = (size_t)kN * kDim;  // stride between s-planes
  const float* base = res + (size_t)b * kS * plane + (size_t)n * kDim;
  float* obase      = out + (size_t)b * kS * plane + (size_t)n * kDim;

  const int d0 = tid * 4;
  const int d1 = tid * 4 + 1024;

  // ---- load residual rows (kept in registers; read exactly once) ----
  float r[kS][8];
  float wv[8];
#pragma unroll
  for (int s = 0; s < kS; ++s) {
    const float* rp = base + (size_t)s * plane;
    const float4 a = *(const float4*)(rp + d0);
    const float4 c = *(const float4*)(rp + d1);
    r[s][0] = a.x; r[s][1] = a.y; r[s][2] = a.z; r[s][3] = a.w;
    r[s][4] = c.x; r[s][5] = c.y; r[s][6] = c.z; r[s][7] = c.w;
  }
  {
    const float4 a = *(const float4*)(norm_w + d0);
    const float4 c = *(const float4*)(norm_w + d1);
    wv[0] = a.x; wv[1] = a.y; wv[2] = a.z; wv[3] = a.w;
    wv[4] = c.x; wv[5] = c.y; wv[6] = c.z; wv[7] = c.w;
  }

  // ---- pass 1: fused block-reduce of {sum, sumsq} per s (8 values) ----
  float p1[8];
#pragma unroll
  for (int s = 0; s < kS; ++s) {
    float sm = 0.f, sq = 0.f;
#pragma unroll
    for (int j = 0; j < 8; ++j) { sm += r[s][j]; sq += r[s][j] * r[s][j]; }
    p1[2 * s] = sm;
    p1[2 * s + 1] = sq;
  }
#pragma unroll
  for (int k = 0; k < 8; ++k) {
#pragma unroll
    for (int off = 32; off > 0; off >>= 1)
      p1[k] += __shfl_xor(p1[k], off, 64);
  }
  if (lane == 0) {
#pragma unroll
    for (int k = 0; k < 8; ++k) red[wave][k] = p1[k];
  }
  __syncthreads();
#pragma unroll
  for (int k = 0; k < 8; ++k)
    p1[k] = red[0][k] + red[1][k] + red[2][k] + red[3][k];
  __syncthreads();  // red is reused below

  float mu[kS], rstd[kS];
#pragma unroll
  for (int s = 0; s < kS; ++s) {
    const float m = p1[2 * s] * (1.f / kDim);
    const float var = p1[2 * s + 1] * (1.f / kDim) - m * m;
    mu[s] = m;
    rstd[s] = rsqrtf(var + kEps);
  }

  // ---- pass 2: fused partials for 5 alpha cols + 1 beta per s (24 values) ----
  float p2[24];
#pragma unroll
  for (int k = 0; k < 24; ++k) p2[k] = 0.f;
#pragma unroll
  for (int half = 0; half < 2; ++half) {
#pragma unroll
    for (int j = 0; j < 4; ++j) {
      const int idx = half * 4 + j;
      const int d = (half ? d1 : d0) + j;
      // alpha_fn row is 5 floats at d*5 (20 B stride — scalar loads; tiny
      // L2-resident array, no alignment for float4)
      const float a0 = alpha_fn[(size_t)d * kSV + 0];
      const float a1 = alpha_fn[(size_t)d * kSV + 1];
      const float a2 = alpha_fn[(size_t)d * kSV + 2];
      const float a3 = alpha_fn[(size_t)d * kSV + 3];
      const float a4 = alpha_fn[(size_t)d * kSV + 4];
      const float bv = beta_fn[d];
#pragma unroll
      for (int s = 0; s < kS; ++s) {
        const float nm = (r[s][idx] - mu[s]) * rstd[s] * wv[idx];
        p2[s * 6 + 0] = fmaf(nm, a0, p2[s * 6 + 0]);
        p2[s * 6 + 1] = fmaf(nm, a1, p2[s * 6 + 1]);
        p2[s * 6 + 2] = fmaf(nm, a2, p2[s * 6 + 2]);
        p2[s * 6 + 3] = fmaf(nm, a3, p2[s * 6 + 3]);
        p2[s * 6 + 4] = fmaf(nm, a4, p2[s * 6 + 4]);
        p2[s * 6 + 5] = fmaf(nm, bv, p2[s * 6 + 5]);
      }
    }
  }
#pragma unroll
  for (int k = 0; k < 24; ++k) {
#pragma unroll
    for (int off = 32; off > 0; off >>= 1)
      p2[k] += __shfl_xor(p2[k], off, 64);
  }
  if (lane == 0) {
#pragma unroll
    for (int k = 0; k < 24; ++k) red[wave][k] = p2[k];
  }
  __syncthreads();

  // ---- finalize alpha/beta on 24 threads (LDS-indexed, not reg-indexed;
  //      avoids runtime-indexed register arrays -> scratch) ----
  if (tid < 24) {
    const float tot = red[0][tid] + red[1][tid] + red[2][tid] + red[3][tid];
    const int s = tid / 6;
    const int q = tid % 6;
    const float t = tanhf(tot);
    float val;
    if (q < 5) val = fmaf(t, alpha_scale_p[0], static_alpha[s * kSV + q]);
    else       val = fmaf(t, beta_scale_p[0], static_beta[s]);
    ab[tid] = val;
  }
  __syncthreads();

  float al[kS][kSV], be[kS];
#pragma unroll
  for (int s = 0; s < kS; ++s) {
#pragma unroll
    for (int t = 0; t < kSV; ++t) al[s][t] = ab[s * 6 + t];  // LDS broadcast
    be[s] = ab[s * 6 + 5];
  }

  // ---- mix + output: out[s_out][d] = beta[s_out]*mix0[d] + mix_{s_out+1}[d],
  //      mix_t[d] = sum_s alpha[s][t] * r[s][d] ----
#pragma unroll
  for (int half = 0; half < 2; ++half) {
    const int dd = half ? d1 : d0;
    float4 ov[kS];
#pragma unroll
    for (int j = 0; j < 4; ++j) {
      const int idx = half * 4 + j;
      const float r0 = r[0][idx], r1 = r[1][idx], r2 = r[2][idx], r3 = r[3][idx];
      const float mix0 = al[0][0] * r0 + al[1][0] * r1 + al[2][0] * r2 + al[3][0] * r3;
#pragma unroll
      for (int so = 0; so < kS; ++so) {
        float t = al[0][so + 1] * r0 + al[1][so + 1] * r1 +
                  al[2][so + 1] * r2 + al[3][so + 1] * r3;
        t = fmaf(be[so], mix0, t);
        (&ov[so].x)[j] = t;
      }
    }
#pragma unroll
    for (int so = 0; so < kS; ++so)
      *(float4*)(obase + (size_t)so * plane + dd) = ov[so];
  }
}

extern "C" void kernel_launch(void* const* d_in, const int* in_sizes, int n_in,
                              void* d_out, int out_size, void* d_ws, size_t ws_size,
                              hipStream_t stream) {
  const float* res    = (const float*)d_in[0];
  const float* norm_w = (const float*)d_in[1];
  const float* sbeta  = (const float*)d_in[2];
  const float* salpha = (const float*)d_in[3];
  const float* afn    = (const float*)d_in[4];
  const float* ascale = (const float*)d_in[5];
  const float* bfn    = (const float*)d_in[6];
  const float* bscale = (const float*)d_in[7];
  float* outp = (float*)d_out;

  hipLaunchKernelGGL(hyperconn_kernel, dim3(kB * kN), dim3(kThreads), 0, stream,
                     res, norm_w, sbeta, salpha, afn, ascale, bfn, bscale, outp);
}

// Round 4
// 447.944 us; speedup vs baseline: 1.0949x; 1.0949x over previous
//
#include <hip/hip_runtime.h>
#include <cstddef>

namespace {
constexpr int kDim = 2048;
constexpr int kS = 4;
constexpr int kSV = 5;   // S + V
constexpr int kB = 4;
constexpr int kN = 2048;
constexpr float kEps = 1e-5f;
constexpr int kThreads = 256;
constexpr int kWaves = kThreads / 64;
constexpr int kNV = 32;  // fused reduction values: per s: {sum, sumsq, 5 alpha dots, 1 beta dot}
constexpr size_t kWcElems = 6 * (size_t)kDim;  // prefolded w*coef, column-major [t][d]
constexpr size_t kWsNeeded = (kWcElems + 6) * sizeof(float);
}

// ---------------- setup: prefold coefficients, compute wa[t] = dot(w, coef_t) ----
__global__ __launch_bounds__(256) void hyperconn_setup(
    const float* __restrict__ norm_w,   // (DIM,)
    const float* __restrict__ alpha_fn, // (DIM, 5)
    const float* __restrict__ beta_fn,  // (DIM,)
    float* __restrict__ ws)             // [6][DIM] wcoef + [6] wa
{
  const int tid = threadIdx.x;
  const int lane = tid & 63;
  const int wave = tid >> 6;
  __shared__ float red[4][6];

  float acc[6] = {0.f, 0.f, 0.f, 0.f, 0.f, 0.f};
#pragma unroll
  for (int rep = 0; rep < kDim / 256; ++rep) {
    const int d = rep * 256 + tid;
    const float w = norm_w[d];
    float c[6];
    c[0] = alpha_fn[(size_t)d * kSV + 0];
    c[1] = alpha_fn[(size_t)d * kSV + 1];
    c[2] = alpha_fn[(size_t)d * kSV + 2];
    c[3] = alpha_fn[(size_t)d * kSV + 3];
    c[4] = alpha_fn[(size_t)d * kSV + 4];
    c[5] = beta_fn[d];
#pragma unroll
    for (int t = 0; t < 6; ++t) {
      const float wc = w * c[t];
      ws[(size_t)t * kDim + d] = wc;
      acc[t] += wc;
    }
  }
#pragma unroll
  for (int t = 0; t < 6; ++t) {
#pragma unroll
    for (int off = 32; off > 0; off >>= 1)
      acc[t] += __shfl_xor(acc[t], off, 64);
  }
  if (lane == 0) {
#pragma unroll
    for (int t = 0; t < 6; ++t) red[wave][t] = acc[t];
  }
  __syncthreads();
  if (tid < 6)
    ws[kWcElems + tid] = red[0][tid] + red[1][tid] + red[2][tid] + red[3][tid];
}

// ---------------- main: one block per (b,n); single fused 32-value reduction ----
__global__ __launch_bounds__(kThreads) void hyperconn_main(
    const float* __restrict__ res,          // (B*S, N, DIM)
    const float* __restrict__ static_beta,  // (S,)
    const float* __restrict__ static_alpha, // (S, SV)
    const float* __restrict__ alpha_scale_p,
    const float* __restrict__ beta_scale_p,
    const float* __restrict__ ws,           // wcoef[6][DIM] + wa[6]
    float* __restrict__ out)
{
  const int bid = blockIdx.x;
  const int b = bid >> 11;        // / kN
  const int n = bid & (kN - 1);
  const int tid = threadIdx.x;
  const int lane = tid & 63;
  const int wave = tid >> 6;

  __shared__ float red[kWaves][kNV];
  __shared__ float ab[24];  // ab[s*6+t], t<5: alpha[s][t]; t==5: beta[s]

  const size_t plane = (size_t)kN * kDim;
  const float* base = res + (size_t)b * kS * plane + (size_t)n * kDim;
  float* obase      = out + (size_t)b * kS * plane + (size_t)n * kDim;

  const int d0 = tid * 4;
  const int d1 = tid * 4 + 1024;

  // ---- load residual rows (registers; read exactly once) ----
  float r[kS][8];
#pragma unroll
  for (int s = 0; s < kS; ++s) {
    const float* rp = base + (size_t)s * plane;
    const float4 a = *(const float4*)(rp + d0);
    const float4 c = *(const float4*)(rp + d1);
    r[s][0] = a.x; r[s][1] = a.y; r[s][2] = a.z; r[s][3] = a.w;
    r[s][4] = c.x; r[s][5] = c.y; r[s][6] = c.z; r[s][7] = c.w;
  }

  // ---- single-pass partials: v[s*8 + q], q: 0=sum 1=sumsq 2..6=alpha dots 7=beta dot
  float v[kNV];
#pragma unroll
  for (int k = 0; k < kNV; ++k) v[k] = 0.f;

#pragma unroll
  for (int half = 0; half < 2; ++half) {
    const int dd = half ? d1 : d0;
    // coalesced prefolded coefficient columns (float4, 16B/lane)
    float4 c0 = *(const float4*)(ws + 0 * kDim + dd);
    float4 c1 = *(const float4*)(ws + 1 * kDim + dd);
    float4 c2 = *(const float4*)(ws + 2 * kDim + dd);
    float4 c3 = *(const float4*)(ws + 3 * kDim + dd);
    float4 c4 = *(const float4*)(ws + 4 * kDim + dd);
    float4 c5 = *(const float4*)(ws + 5 * kDim + dd);
    const float* p0 = &c0.x; const float* p1 = &c1.x; const float* p2 = &c2.x;
    const float* p3 = &c3.x; const float* p4 = &c4.x; const float* p5 = &c5.x;
#pragma unroll
    for (int j = 0; j < 4; ++j) {
      const int idx = half * 4 + j;
      const float w0 = p0[j], w1 = p1[j], w2 = p2[j];
      const float w3 = p3[j], w4 = p4[j], w5 = p5[j];
#pragma unroll
      for (int s = 0; s < kS; ++s) {
        const float rv = r[s][idx];
        v[s * 8 + 0] += rv;
        v[s * 8 + 1] = fmaf(rv, rv, v[s * 8 + 1]);
        v[s * 8 + 2] = fmaf(rv, w0, v[s * 8 + 2]);
        v[s * 8 + 3] = fmaf(rv, w1, v[s * 8 + 3]);
        v[s * 8 + 4] = fmaf(rv, w2, v[s * 8 + 4]);
        v[s * 8 + 5] = fmaf(rv, w3, v[s * 8 + 5]);
        v[s * 8 + 6] = fmaf(rv, w4, v[s * 8 + 6]);
        v[s * 8 + 7] = fmaf(rv, w5, v[s * 8 + 7]);
      }
    }
  }

  // ---- value-split butterfly: 32 values over 64 lanes in 32 shuffles.
  // After 5 halving stages + xor32, lane l holds full sum of value (l & 31).
#pragma unroll
  for (int st = 0; st < 5; ++st) {
    const int mask = 1 << st;
    const int half_n = kNV >> (st + 1);
#pragma unroll
    for (int i = 0; i < half_n; ++i) {
      const float send = (lane & mask) ? v[2 * i] : v[2 * i + 1];
      const float keep = (lane & mask) ? v[2 * i + 1] : v[2 * i];
      v[i] = keep + __shfl_xor(send, mask, 64);
    }
  }
  v[0] += __shfl_xor(v[0], 32, 64);

  if (lane < kNV) red[wave][lane] = v[0];
  __syncthreads();

  // ---- finalize alpha/beta on 32 threads ----
  if (tid < kNV) {
    const int s = tid >> 3;
    const int q = tid & 7;
    if (q >= 2) {
      const float sum = red[0][s * 8] + red[1][s * 8] + red[2][s * 8] + red[3][s * 8];
      const float sq  = red[0][s * 8 + 1] + red[1][s * 8 + 1] + red[2][s * 8 + 1] + red[3][s * 8 + 1];
      const float tot = red[0][tid] + red[1][tid] + red[2][tid] + red[3][tid];
      const float mu = sum * (1.f / kDim);
      const float var = sq * (1.f / kDim) - mu * mu;
      const float rstd = rsqrtf(var + kEps);
      const float wa = ws[kWcElems + (q - 2)];
      const float dotn = (tot - mu * wa) * rstd;
      const float t = tanhf(dotn);
      const float val = (q < 7)
          ? fmaf(t, alpha_scale_p[0], static_alpha[s * kSV + (q - 2)])
          : fmaf(t, beta_scale_p[0], static_beta[s]);
      ab[s * 6 + (q - 2)] = val;   // q==7 -> slot 5 (beta)
    }
  }
  __syncthreads();

  float al[kS][kSV], be[kS];
#pragma unroll
  for (int s = 0; s < kS; ++s) {
#pragma unroll
    for (int t = 0; t < kSV; ++t) al[s][t] = ab[s * 6 + t];  // LDS broadcast
    be[s] = ab[s * 6 + 5];
  }

  // ---- mix + store ----
#pragma unroll
  for (int half = 0; half < 2; ++half) {
    const int dd = half ? d1 : d0;
    float4 ov[kS];
#pragma unroll
    for (int j = 0; j < 4; ++j) {
      const int idx = half * 4 + j;
      const float r0 = r[0][idx], r1 = r[1][idx], r2 = r[2][idx], r3 = r[3][idx];
      const float mix0 = al[0][0] * r0 + al[1][0] * r1 + al[2][0] * r2 + al[3][0] * r3;
#pragma unroll
      for (int so = 0; so < kS; ++so) {
        float t = al[0][so + 1] * r0 + al[1][so + 1] * r1 +
                  al[2][so + 1] * r2 + al[3][so + 1] * r3;
        t = fmaf(be[so], mix0, t);
        (&ov[so].x)[j] = t;
      }
    }
#pragma unroll
    for (int so = 0; so < kS; ++so)
      *(float4*)(obase + (size_t)so * plane + dd) = ov[so];
  }
}

// ---------------- fallback (validated round-3 kernel) if ws is too small ----
__global__ __launch_bounds__(kThreads) void hyperconn_fallback(
    const float* __restrict__ res, const float* __restrict__ norm_w,
    const float* __restrict__ static_beta, const float* __restrict__ static_alpha,
    const float* __restrict__ alpha_fn, const float* __restrict__ alpha_scale_p,
    const float* __restrict__ beta_fn, const float* __restrict__ beta_scale_p,
    float* __restrict__ out)
{
  const int bid = blockIdx.x;
  const int b = bid / kN;
  const int n = bid % kN;
  const int tid = threadIdx.x;
  const int lane = tid & 63;
  const int wave = tid >> 6;
  __shared__ float red[kWaves][24];
  __shared__ float ab[24];
  const size_t plane = (size_t)kN * kDim;
  const float* base = res + (size_t)b * kS * plane + (size_t)n * kDim;
  float* obase      = out + (size_t)b * kS * plane + (size_t)n * kDim;
  const int d0 = tid * 4;
  const int d1 = tid * 4 + 1024;
  float r[kS][8];
  float wv[8];
#pragma unroll
  for (int s = 0; s < kS; ++s) {
    const float* rp = base + (size_t)s * plane;
    const float4 a = *(const float4*)(rp + d0);
    const float4 c = *(const float4*)(rp + d1);
    r[s][0] = a.x; r[s][1] = a.y; r[s][2] = a.z; r[s][3] = a.w;
    r[s][4] = c.x; r[s][5] = c.y; r[s][6] = c.z; r[s][7] = c.w;
  }
  {
    const float4 a = *(const float4*)(norm_w + d0);
    const float4 c = *(const float4*)(norm_w + d1);
    wv[0] = a.x; wv[1] = a.y; wv[2] = a.z; wv[3] = a.w;
    wv[4] = c.x; wv[5] = c.y; wv[6] = c.z; wv[7] = c.w;
  }
  float p1[8];
#pragma unroll
  for (int s = 0; s < kS; ++s) {
    float sm = 0.f, sq = 0.f;
#pragma unroll
    for (int j = 0; j < 8; ++j) { sm += r[s][j]; sq += r[s][j] * r[s][j]; }
    p1[2 * s] = sm; p1[2 * s + 1] = sq;
  }
#pragma unroll
  for (int k = 0; k < 8; ++k)
#pragma unroll
    for (int off = 32; off > 0; off >>= 1)
      p1[k] += __shfl_xor(p1[k], off, 64);
  if (lane == 0)
#pragma unroll
    for (int k = 0; k < 8; ++k) red[wave][k] = p1[k];
  __syncthreads();
#pragma unroll
  for (int k = 0; k < 8; ++k)
    p1[k] = red[0][k] + red[1][k] + red[2][k] + red[3][k];
  __syncthreads();
  float mu[kS], rstd[kS];
#pragma unroll
  for (int s = 0; s < kS; ++s) {
    const float m = p1[2 * s] * (1.f / kDim);
    const float var = p1[2 * s + 1] * (1.f / kDim) - m * m;
    mu[s] = m; rstd[s] = rsqrtf(var + kEps);
  }
  float p2[24];
#pragma unroll
  for (int k = 0; k < 24; ++k) p2[k] = 0.f;
#pragma unroll
  for (int half = 0; half < 2; ++half) {
#pragma unroll
    for (int j = 0; j < 4; ++j) {
      const int idx = half * 4 + j;
      const int d = (half ? d1 : d0) + j;
      const float a0 = alpha_fn[(size_t)d * kSV + 0];
      const float a1 = alpha_fn[(size_t)d * kSV + 1];
      const float a2 = alpha_fn[(size_t)d * kSV + 2];
      const float a3 = alpha_fn[(size_t)d * kSV + 3];
      const float a4 = alpha_fn[(size_t)d * kSV + 4];
      const float bv = beta_fn[d];
#pragma unroll
      for (int s = 0; s < kS; ++s) {
        const float nm = (r[s][idx] - mu[s]) * rstd[s] * wv[idx];
        p2[s * 6 + 0] = fmaf(nm, a0, p2[s * 6 + 0]);
        p2[s * 6 + 1] = fmaf(nm, a1, p2[s * 6 + 1]);
        p2[s * 6 + 2] = fmaf(nm, a2, p2[s * 6 + 2]);
        p2[s * 6 + 3] = fmaf(nm, a3, p2[s * 6 + 3]);
        p2[s * 6 + 4] = fmaf(nm, a4, p2[s * 6 + 4]);
        p2[s * 6 + 5] = fmaf(nm, bv, p2[s * 6 + 5]);
      }
    }
  }
#pragma unroll
  for (int k = 0; k < 24; ++k)
#pragma unroll
    for (int off = 32; off > 0; off >>= 1)
      p2[k] += __shfl_xor(p2[k], off, 64);
  if (lane == 0)
#pragma unroll
    for (int k = 0; k < 24; ++k) red[wave][k] = p2[k];
  __syncthreads();
  if (tid < 24) {
    const float tot = red[0][tid] + red[1][tid] + red[2][tid] + red[3][tid];
    const int s = tid / 6; const int q = tid % 6;
    const float t = tanhf(tot);
    float val;
    if (q < 5) val = fmaf(t, alpha_scale_p[0], static_alpha[s * kSV + q]);
    else       val = fmaf(t, beta_scale_p[0], static_beta[s]);
    ab[tid] = val;
  }
  __syncthreads();
  float al[kS][kSV], be[kS];
#pragma unroll
  for (int s = 0; s < kS; ++s) {
#pragma unroll
    for (int t = 0; t < kSV; ++t) al[s][t] = ab[s * 6 + t];
    be[s] = ab[s * 6 + 5];
  }
#pragma unroll
  for (int half = 0; half < 2; ++half) {
    const int dd = half ? d1 : d0;
    float4 ov[kS];
#pragma unroll
    for (int j = 0; j < 4; ++j) {
      const int idx = half * 4 + j;
      const float r0 = r[0][idx], r1 = r[1][idx], r2 = r[2][idx], r3 = r[3][idx];
      const float mix0 = al[0][0] * r0 + al[1][0] * r1 + al[2][0] * r2 + al[3][0] * r3;
#pragma unroll
      for (int so = 0; so < kS; ++so) {
        float t = al[0][so + 1] * r0 + al[1][so + 1] * r1 +
                  al[2][so + 1] * r2 + al[3][so + 1] * r3;
        t = fmaf(be[so], mix0, t);
        (&ov[so].x)[j] = t;
      }
    }
#pragma unroll
    for (int so = 0; so < kS; ++so)
      *(float4*)(obase + (size_t)so * plane + dd) = ov[so];
  }
}

extern "C" void kernel_launch(void* const* d_in, const int* in_sizes, int n_in,
                              void* d_out, int out_size, void* d_ws, size_t ws_size,
                              hipStream_t stream) {
  const float* res    = (const float*)d_in[0];
  const float* norm_w = (const float*)d_in[1];
  const float* sbeta  = (const float*)d_in[2];
  const float* salpha = (const float*)d_in[3];
  const float* afn    = (const float*)d_in[4];
  const float* ascale = (const float*)d_in[5];
  const float* bfn    = (const float*)d_in[6];
  const float* bscale = (const float*)d_in[7];
  float* outp = (float*)d_out;

  if (ws_size >= kWsNeeded) {
    hipLaunchKernelGGL(hyperconn_setup, dim3(1), dim3(256), 0, stream,
                       norm_w, afn, bfn, (float*)d_ws);
    hipLaunchKernelGGL(hyperconn_main, dim3(kB * kN), dim3(kThreads), 0, stream,
                       res, sbeta, salpha, ascale, bscale, (const float*)d_ws, outp);
  } else {
    hipLaunchKernelGGL(hyperconn_fallback, dim3(kB * kN), dim3(kThreads), 0, stream,
                       res, norm_w, sbeta, salpha, afn, ascale, bfn, bscale, outp);
  }
}